// Round 4
// baseline (8408.551 us; speedup 1.0000x reference)
//
#include <hip/hip_runtime.h>
#include <math.h>

#define BATCH 16
#define SEQ 512
#define DIM 2048
#define HID 1024
#define NPAIRS 128
#define TLEN 384
#define NUN 256
#define HPASS 512    // token rows per h-pass (16 passes)
#define MPASS 512    // pair rows per merger pass (4 passes)

// ---------------------------------------------------------------------------
// GEMM 1 (per pass): pre = x @ imp_w1 + b1 (fp64 exact, rounded to f32),
// then h = gelu_f64(pre_f32) rounded to f32.  Mirrors ref's f32 h store.
// ---------------------------------------------------------------------------
__global__ __launch_bounds__(256)
void cc_gemm_h(const float* __restrict__ A, const float* __restrict__ B,
               const float* __restrict__ bias, float* __restrict__ C) {
  const int N = HID, K = DIM;
  __shared__ float As[16][68];
  __shared__ float Bs[16][64];
  int tid = threadIdx.x;
  int tx = tid % 16, ty = tid / 16;
  int m0 = blockIdx.y * 64, n0 = blockIdx.x * 64;
  double acc[4][4] = {};
  for (int k0 = 0; k0 < K; k0 += 16) {
#pragma unroll
    for (int u = 0; u < 4; ++u) {
      int l = tid + u * 256;
      int r = l / 16, k = l % 16;
      As[k][r] = A[(size_t)(m0 + r) * K + k0 + k];
    }
#pragma unroll
    for (int u = 0; u < 4; ++u) {
      int l = tid + u * 256;
      int k = l / 64, n = l % 64;
      Bs[k][n] = B[(size_t)(k0 + k) * N + n0 + n];
    }
    __syncthreads();
#pragma unroll
    for (int k = 0; k < 16; ++k) {
      float a[4], b[4];
#pragma unroll
      for (int i = 0; i < 4; ++i) a[i] = As[k][ty * 4 + i];
#pragma unroll
      for (int j = 0; j < 4; ++j) b[j] = Bs[k][tx * 4 + j];
#pragma unroll
      for (int i = 0; i < 4; ++i)
#pragma unroll
        for (int j = 0; j < 4; ++j)
          acc[i][j] = fma((double)a[i], (double)b[j], acc[i][j]);
    }
    __syncthreads();
  }
#pragma unroll
  for (int i = 0; i < 4; ++i)
#pragma unroll
    for (int j = 0; j < 4; ++j) {
      int m = m0 + ty * 4 + i, n = n0 + tx * 4 + j;
      float pre = (float)(acc[i][j] + (double)bias[n]);     // f32 store point
      double v = (double)pre;
      double g = 0.5 * v * (1.0 + erf(v * 0.70710678118654752440));
      C[(size_t)m * N + n] = (float)g;                      // f32 store point
    }
}

// ---------------------------------------------------------------------------
// imp = sigmoid(h @ imp_w2 + b2); logit rounded to f32, imp stored f32
// ---------------------------------------------------------------------------
__global__ __launch_bounds__(256)
void cc_imp2(const float* __restrict__ h, const float* __restrict__ w2,
             const float* __restrict__ b2, float* __restrict__ imp) {
  int row = blockIdx.x, tid = threadIdx.x;
  __shared__ double red[256];
  double s = 0.0;
  const float* hr = h + (size_t)row * HID;
  for (int k = tid; k < HID; k += 256) s = fma((double)hr[k], (double)w2[k], s);
  red[tid] = s;
  __syncthreads();
  for (int off = 128; off > 0; off >>= 1) {
    if (tid < off) red[tid] += red[tid + off];
    __syncthreads();
  }
  if (tid == 0) {
    float logit = (float)(red[0] + (double)b2[0]);          // f32 store point
    double sg = 1.0 / (1.0 + exp(-(double)logit));
    imp[row] = (float)sg;                                   // f32 store point
  }
}

// ---------------------------------------------------------------------------
// per-batch min-max normalize in f32, then w = max(norm, 0.1f)
// ---------------------------------------------------------------------------
__global__ __launch_bounds__(512)
void cc_minmax(const float* __restrict__ imp, float* __restrict__ w) {
  int b = blockIdx.x, tid = threadIdx.x;
  __shared__ float mn[512], mx[512];
  float v = imp[b * SEQ + tid];
  mn[tid] = v; mx[tid] = v;
  __syncthreads();
  for (int off = 256; off > 0; off >>= 1) {
    if (tid < off) {
      mn[tid] = fminf(mn[tid], mn[tid + off]);
      mx[tid] = fmaxf(mx[tid], mx[tid + off]);
    }
    __syncthreads();
  }
  float lo = mn[0], hi = mx[0];
  float nv = (hi > lo) ? (v - lo) / (hi - lo) : v;          // pure f32 ops
  w[b * SEQ + tid] = fmaxf(nv, 0.1f);
}

// ---------------------------------------------------------------------------
// row L2 norms of x: exact f64 sumsq, sqrt, rounded to f32, clamp 1e-12f
// ---------------------------------------------------------------------------
__global__ __launch_bounds__(256)
void cc_rownorm(const float* __restrict__ x, float* __restrict__ rn) {
  int row = blockIdx.x, tid = threadIdx.x;
  __shared__ double red[256];
  double s = 0.0;
  const float* xr = x + (size_t)row * DIM;
  for (int k = tid; k < DIM; k += 256) {
    double v = xr[k];
    s = fma(v, v, s);
  }
  red[tid] = s;
  __syncthreads();
  for (int off = 128; off > 0; off >>= 1) {
    if (tid < off) red[tid] += red[tid + off];
    __syncthreads();
  }
  if (tid == 0) rn[row] = fmaxf((float)sqrt(red[0]), 1e-12f);
}

// ---------------------------------------------------------------------------
// score[b,s,t]: xn = x/rn (f32 div at load), sim = f64-exact dot -> f32,
// wprod = w_s*w_t (f32 mul), score = sim/wprod (f32 div); diag = -1.0f
// ---------------------------------------------------------------------------
__global__ __launch_bounds__(256)
void cc_gemm_score(const float* __restrict__ X, const float* __restrict__ rn,
                   const float* __restrict__ w, float* __restrict__ score) {
  const int b = blockIdx.z;
  __shared__ float As[16][68];
  __shared__ float Bs[16][68];
  int tid = threadIdx.x;
  int tx = tid % 16, ty = tid / 16;
  int s0 = blockIdx.y * 64, t0 = blockIdx.x * 64;
  const float* Xb = X + (size_t)b * SEQ * DIM;
  const float* rnb = rn + b * SEQ;
  double acc[4][4] = {};
  for (int k0 = 0; k0 < DIM; k0 += 16) {
#pragma unroll
    for (int u = 0; u < 4; ++u) {
      int l = tid + u * 256;
      int r = l / 16, k = l % 16;
      // f32 division: bit-exact xn as in reference
      As[k][r] = Xb[(size_t)(s0 + r) * DIM + k0 + k] / rnb[s0 + r];
      Bs[k][r] = Xb[(size_t)(t0 + r) * DIM + k0 + k] / rnb[t0 + r];
    }
    __syncthreads();
#pragma unroll
    for (int k = 0; k < 16; ++k) {
      float a[4], bb[4];
#pragma unroll
      for (int i = 0; i < 4; ++i) a[i] = As[k][ty * 4 + i];
#pragma unroll
      for (int j = 0; j < 4; ++j) bb[j] = Bs[k][tx * 4 + j];
#pragma unroll
      for (int i = 0; i < 4; ++i)
#pragma unroll
        for (int j = 0; j < 4; ++j)
          acc[i][j] = fma((double)a[i], (double)bb[j], acc[i][j]);
    }
    __syncthreads();
  }
#pragma unroll
  for (int i = 0; i < 4; ++i)
#pragma unroll
    for (int j = 0; j < 4; ++j) {
      int s = s0 + ty * 4 + i, t = t0 + tx * 4 + j;
      float v;
      if (s == t) v = -1.0f;
      else {
        float sim = (float)acc[i][j];                       // f32 store point
        float wp = w[b * SEQ + s] * w[b * SEQ + t];         // f32 multiply
        v = sim / wp;                                       // f32 divide
      }
      score[((size_t)b * SEQ + s) * SEQ + t] = v;
    }
}

// ---------------------------------------------------------------------------
// Greedy pair selection on f32 scores (one block per batch).
// Tie-breaks (smallest row, then smallest col) match flat jnp.argmax.
// ---------------------------------------------------------------------------
__global__ __launch_bounds__(256)
void cc_greedy(const float* __restrict__ score, int* __restrict__ pi,
               int* __restrict__ pj, unsigned char* __restrict__ availg) {
  const int b = blockIdx.x;
  const float* S = score + (size_t)b * SEQ * SEQ;
  __shared__ float rmax[SEQ];
  __shared__ int rarg[SEQ];
  __shared__ unsigned char avail[SEQ];
  __shared__ int list[SEQ];
  __shared__ float redV[256];
  __shared__ int redI[256];
  __shared__ int cnt, si, sj;
  int tid = threadIdx.x;

  for (int rr = 0; rr < 2; ++rr) {
    int r = tid + rr * 256;
    avail[r] = 1;
    const float* row = S + (size_t)r * SEQ;
    float best = -INFINITY; int barg = 0;
    for (int c = 0; c < SEQ; ++c) {
      float v = row[c];
      if (v > best) { best = v; barg = c; }
    }
    rmax[r] = best; rarg[r] = barg;
  }
  __syncthreads();

  for (int t = 0; t < NPAIRS; ++t) {
    float bv = -INFINITY; int bi = SEQ;
    for (int rr = 0; rr < 2; ++rr) {
      int r = tid + rr * 256;
      if (avail[r]) {
        float v = rmax[r];
        if (v > bv || (v == bv && r < bi)) { bv = v; bi = r; }
      }
    }
    redV[tid] = bv; redI[tid] = bi;
    __syncthreads();
    for (int s = 128; s > 0; s >>= 1) {
      if (tid < s) {
        float v2 = redV[tid + s]; int i2 = redI[tid + s];
        if (v2 > redV[tid] || (v2 == redV[tid] && i2 < redI[tid])) {
          redV[tid] = v2; redI[tid] = i2;
        }
      }
      __syncthreads();
    }
    if (tid == 0) {
      int i = redI[0];
      int j = rarg[i];
      si = i; sj = j;
      pi[b * NPAIRS + t] = i;
      pj[b * NPAIRS + t] = j;
      avail[i] = 0; avail[j] = 0;
      cnt = 0;
    }
    __syncthreads();
    for (int rr = 0; rr < 2; ++rr) {
      int r = tid + rr * 256;
      if (avail[r] && (rarg[r] == si || rarg[r] == sj)) {
        int p = atomicAdd(&cnt, 1);
        list[p] = r;
      }
    }
    __syncthreads();
    int nw = cnt;
    int wave = tid >> 6, lane = tid & 63;
    for (int q = wave; q < nw; q += 4) {
      int r = list[q];
      const float* row = S + (size_t)r * SEQ;
      float best = -INFINITY; int barg = SEQ;
      for (int c = lane; c < SEQ; c += 64) {
        if (avail[c]) {
          float v = row[c];
          if (v > best || (v == best && c < barg)) { best = v; barg = c; }
        }
      }
      for (int off = 32; off > 0; off >>= 1) {
        float ov = __shfl_down(best, off, 64);
        int oc = __shfl_down(barg, off, 64);
        if (ov > best || (ov == best && oc < barg)) { best = ov; barg = oc; }
      }
      if (lane == 0) { rmax[r] = best; rarg[r] = barg; }
    }
    __syncthreads();
  }
  for (int rr = 0; rr < 2; ++rr) {
    int r = tid + rr * 256;
    availg[b * SEQ + r] = avail[r];
  }
}

// ---------------------------------------------------------------------------
// unmerged index list via prefix sum (ascending order)
// ---------------------------------------------------------------------------
__global__ __launch_bounds__(512)
void cc_unmerged(const unsigned char* __restrict__ availg, int* __restrict__ un) {
  int b = blockIdx.x, tid = threadIdx.x;
  __shared__ int ps[SEQ];
  int flag = availg[b * SEQ + tid];
  ps[tid] = flag;
  __syncthreads();
  for (int off = 1; off < SEQ; off <<= 1) {
    int v = (tid >= off) ? ps[tid - off] : 0;
    __syncthreads();
    ps[tid] += v;
    __syncthreads();
  }
  int pos = ps[tid] - flag;
  if (flag && pos < NUN) un[b * NUN + pos] = tid;
}

// ---------------------------------------------------------------------------
// copy unmerged tokens to out rows [128, 384)
// ---------------------------------------------------------------------------
__global__ __launch_bounds__(256)
void cc_unmerged_copy(const float* __restrict__ x, const int* __restrict__ un,
                      float* __restrict__ out) {
  int idx = blockIdx.x;
  int b = idx / NUN, u_ = idx % NUN;
  int s = un[idx];
  const float4* src = (const float4*)(x + ((size_t)b * SEQ + s) * DIM);
  float4* dst = (float4*)(out + ((size_t)b * TLEN + NPAIRS + u_) * DIM);
  for (int u = threadIdx.x; u < DIM / 4; u += 256) dst[u] = src[u];
}

// ---------------------------------------------------------------------------
// GEMM (per pass): m1 = gelu(pair @ mrg_w1 + b1); pair rows gathered from x
// via pi/pj on the fly. fp32 accumulate (threshold is generous here).
// ---------------------------------------------------------------------------
__global__ __launch_bounds__(256)
void cc_gemm_m1f(const float* __restrict__ x, const int* __restrict__ pi,
                 const int* __restrict__ pj, const float* __restrict__ B,
                 const float* __restrict__ bias, float* __restrict__ C,
                 int mbase) {
  const int N = DIM, K = 2 * DIM;
  __shared__ float As[16][68];
  __shared__ float Bs[16][64];
  int tid = threadIdx.x;
  int tx = tid % 16, ty = tid / 16;
  int m0 = blockIdx.y * 64, n0 = blockIdx.x * 64;
  float acc[4][4] = {};
  for (int k0 = 0; k0 < K; k0 += 16) {
#pragma unroll
    for (int u = 0; u < 4; ++u) {
      int l = tid + u * 256;
      int r = l / 16, k = l % 16;
      int mg = mbase + m0 + r;
      int bb = mg / NPAIRS;
      int kk = k0 + k;
      int tok = (kk < DIM) ? pi[mg] : pj[mg];
      int kc = (kk < DIM) ? kk : kk - DIM;
      As[k][r] = x[((size_t)bb * SEQ + tok) * DIM + kc];
    }
#pragma unroll
    for (int u = 0; u < 4; ++u) {
      int l = tid + u * 256;
      int k = l / 64, n = l % 64;
      Bs[k][n] = B[(size_t)(k0 + k) * N + n0 + n];
    }
    __syncthreads();
#pragma unroll
    for (int k = 0; k < 16; ++k) {
      float a[4], b[4];
#pragma unroll
      for (int i = 0; i < 4; ++i) a[i] = As[k][ty * 4 + i];
#pragma unroll
      for (int j = 0; j < 4; ++j) b[j] = Bs[k][tx * 4 + j];
#pragma unroll
      for (int i = 0; i < 4; ++i)
#pragma unroll
        for (int j = 0; j < 4; ++j)
          acc[i][j] = fmaf(a[i], b[j], acc[i][j]);
    }
    __syncthreads();
  }
#pragma unroll
  for (int i = 0; i < 4; ++i)
#pragma unroll
    for (int j = 0; j < 4; ++j) {
      int m = m0 + ty * 4 + i, n = n0 + tx * 4 + j;
      double v = (double)acc[i][j] + (double)bias[n];
      double g = 0.5 * v * (1.0 + erf(v * 0.70710678118654752440));
      C[(size_t)m * N + n] = (float)g;
    }
}

// ---------------------------------------------------------------------------
// GEMM (per pass): merged = m1 @ mrg_w2 + b2, scattered into out rows [0,128)
// ---------------------------------------------------------------------------
__global__ __launch_bounds__(256)
void cc_gemm_m2c(const float* __restrict__ A, const float* __restrict__ B,
                 const float* __restrict__ bias, float* __restrict__ out,
                 int mbase) {
  const int N = DIM, K = DIM;
  __shared__ float As[16][68];
  __shared__ float Bs[16][64];
  int tid = threadIdx.x;
  int tx = tid % 16, ty = tid / 16;
  int m0 = blockIdx.y * 64, n0 = blockIdx.x * 64;
  float acc[4][4] = {};
  for (int k0 = 0; k0 < K; k0 += 16) {
#pragma unroll
    for (int u = 0; u < 4; ++u) {
      int l = tid + u * 256;
      int r = l / 16, k = l % 16;
      As[k][r] = A[(size_t)(m0 + r) * K + k0 + k];
    }
#pragma unroll
    for (int u = 0; u < 4; ++u) {
      int l = tid + u * 256;
      int k = l / 64, n = l % 64;
      Bs[k][n] = B[(size_t)(k0 + k) * N + n0 + n];
    }
    __syncthreads();
#pragma unroll
    for (int k = 0; k < 16; ++k) {
      float a[4], b[4];
#pragma unroll
      for (int i = 0; i < 4; ++i) a[i] = As[k][ty * 4 + i];
#pragma unroll
      for (int j = 0; j < 4; ++j) b[j] = Bs[k][tx * 4 + j];
#pragma unroll
      for (int i = 0; i < 4; ++i)
#pragma unroll
        for (int j = 0; j < 4; ++j)
          acc[i][j] = fmaf(a[i], b[j], acc[i][j]);
    }
    __syncthreads();
  }
#pragma unroll
  for (int i = 0; i < 4; ++i)
#pragma unroll
    for (int j = 0; j < 4; ++j) {
      int m = m0 + ty * 4 + i, n = n0 + tx * 4 + j;
      int mg = mbase + m;
      int bb = mg / NPAIRS, p = mg % NPAIRS;
      float v = acc[i][j] + bias[n];
      out[((size_t)bb * TLEN + p) * N + n] = v;
    }
}

extern "C" void kernel_launch(void* const* d_in, const int* in_sizes, int n_in,
                              void* d_out, int out_size, void* d_ws, size_t ws_size,
                              hipStream_t stream) {
  const float* x      = (const float*)d_in[0];
  const float* imp_w1 = (const float*)d_in[1];
  const float* imp_b1 = (const float*)d_in[2];
  const float* imp_w2 = (const float*)d_in[3];
  const float* imp_b2 = (const float*)d_in[4];
  const float* mrg_w1 = (const float*)d_in[5];
  const float* mrg_b1 = (const float*)d_in[6];
  const float* mrg_w2 = (const float*)d_in[7];
  const float* mrg_b2 = (const float*)d_in[8];
  float* out = (float*)d_out;

  // score (16 MB f32) lives in d_out (48 MB) — fully consumed by greedy/
  // unmerged before any output writes begin.
  float* score = (float*)d_out;

  // workspace: < 4.5 MB total
  char* ws = (char*)d_ws;
  float* hbuf  = (float*)ws;                          // 2 MB (reused as m1buf)
  float* m1buf = (float*)ws;                          // 4 MB (after h phase)
  char* sm = ws + ((size_t)4 << 20);
  float* imp = (float*)sm;              sm += (size_t)BATCH * SEQ * 4;
  float* wv  = (float*)sm;              sm += (size_t)BATCH * SEQ * 4;
  float* rn  = (float*)sm;              sm += (size_t)BATCH * SEQ * 4;
  int* pi    = (int*)sm;                sm += (size_t)BATCH * NPAIRS * 4;
  int* pj    = (int*)sm;                sm += (size_t)BATCH * NPAIRS * 4;
  unsigned char* avail = (unsigned char*)sm; sm += (size_t)BATCH * SEQ;
  int* un    = (int*)sm;                sm += (size_t)BATCH * NUN * 4;

  cc_rownorm<<<BATCH * SEQ, 256, 0, stream>>>(x, rn);
  for (int p = 0; p < (BATCH * SEQ) / HPASS; ++p) {
    cc_gemm_h<<<dim3(HID / 64, HPASS / 64), 256, 0, stream>>>(
        x + (size_t)p * HPASS * DIM, imp_w1, imp_b1, hbuf);
    cc_imp2<<<HPASS, 256, 0, stream>>>(hbuf, imp_w2, imp_b2, imp + (size_t)p * HPASS);
  }
  cc_minmax<<<BATCH, 512, 0, stream>>>(imp, wv);
  cc_gemm_score<<<dim3(SEQ / 64, SEQ / 64, BATCH), 256, 0, stream>>>(x, rn, wv, score);
  cc_greedy<<<BATCH, 256, 0, stream>>>(score, pi, pj, avail);
  cc_unmerged<<<BATCH, SEQ, 0, stream>>>(avail, un);
  // score (in d_out) is dead from here on; start writing outputs.
  cc_unmerged_copy<<<BATCH * NUN, 256, 0, stream>>>(x, un, out);
  for (int p = 0; p < (BATCH * NPAIRS) / MPASS; ++p) {
    cc_gemm_m1f<<<dim3(DIM / 64, MPASS / 64), 256, 0, stream>>>(
        x, pi, pj, mrg_w1, mrg_b1, m1buf, p * MPASS);
    cc_gemm_m2c<<<dim3(DIM / 64, MPASS / 64), 256, 0, stream>>>(
        m1buf, mrg_w2, mrg_b2, out, p * MPASS);
  }
}

// Round 5
// 4791.308 us; speedup vs baseline: 1.7550x; 1.7550x over previous
//
#include <hip/hip_runtime.h>
#include <math.h>

#define BATCH 16
#define SEQ 512
#define DIM 2048
#define HID 1024
#define NPAIRS 128
#define TLEN 384
#define NUN 256
#define BK 32

// ---------------------------------------------------------------------------
// GEMM 1: h = gelu(x @ imp_w1 + b1). fp64 accumulate (ascending k — bit-exact
// vs round-4), f64 tiles in LDS (convert once at staging). 64x64 tile, BK=32.
// ---------------------------------------------------------------------------
__global__ __launch_bounds__(256)
void cc_gemm_h(const float* __restrict__ A, const float* __restrict__ Bw,
               const float* __restrict__ bias, float* __restrict__ C) {
  const int N = HID, K = DIM;
  __shared__ double As[BK][66];
  __shared__ double Bs[BK][66];
  int tid = threadIdx.x;
  int tx = tid % 16, ty = tid / 16;
  int m0 = blockIdx.y * 64, n0 = blockIdx.x * 64;
  double acc[4][4] = {};
  for (int k0 = 0; k0 < K; k0 += BK) {
#pragma unroll
    for (int u = 0; u < 8; ++u) {
      int l = tid + u * 256;
      int r = l >> 5, k = l & 31;            // A: 64 rows x 32 k
      As[k][r] = (double)A[(size_t)(m0 + r) * K + k0 + k];
      int kb = l >> 6, n = l & 63;           // B: 32 k x 64 n
      Bs[kb][n] = (double)Bw[(size_t)(k0 + kb) * N + n0 + n];
    }
    __syncthreads();
#pragma unroll
    for (int k = 0; k < BK; ++k) {
      double a0 = As[k][ty * 4 + 0], a1 = As[k][ty * 4 + 1];
      double a2 = As[k][ty * 4 + 2], a3 = As[k][ty * 4 + 3];
      double b0 = Bs[k][tx * 4 + 0], b1 = Bs[k][tx * 4 + 1];
      double b2 = Bs[k][tx * 4 + 2], b3 = Bs[k][tx * 4 + 3];
      acc[0][0] = fma(a0, b0, acc[0][0]); acc[0][1] = fma(a0, b1, acc[0][1]);
      acc[0][2] = fma(a0, b2, acc[0][2]); acc[0][3] = fma(a0, b3, acc[0][3]);
      acc[1][0] = fma(a1, b0, acc[1][0]); acc[1][1] = fma(a1, b1, acc[1][1]);
      acc[1][2] = fma(a1, b2, acc[1][2]); acc[1][3] = fma(a1, b3, acc[1][3]);
      acc[2][0] = fma(a2, b0, acc[2][0]); acc[2][1] = fma(a2, b1, acc[2][1]);
      acc[2][2] = fma(a2, b2, acc[2][2]); acc[2][3] = fma(a2, b3, acc[2][3]);
      acc[3][0] = fma(a3, b0, acc[3][0]); acc[3][1] = fma(a3, b1, acc[3][1]);
      acc[3][2] = fma(a3, b2, acc[3][2]); acc[3][3] = fma(a3, b3, acc[3][3]);
    }
    __syncthreads();
  }
#pragma unroll
  for (int i = 0; i < 4; ++i)
#pragma unroll
    for (int j = 0; j < 4; ++j) {
      int m = m0 + ty * 4 + i, n = n0 + tx * 4 + j;
      float pre = (float)(acc[i][j] + (double)bias[n]);     // f32 store point
      double v = (double)pre;
      double g = 0.5 * v * (1.0 + erf(v * 0.70710678118654752440));
      C[(size_t)m * N + n] = (float)g;                      // f32 store point
    }
}

// ---------------------------------------------------------------------------
// imp = sigmoid(h @ imp_w2 + b2); logit rounded to f32, imp stored f32
// ---------------------------------------------------------------------------
__global__ __launch_bounds__(256)
void cc_imp2(const float* __restrict__ h, const float* __restrict__ w2,
             const float* __restrict__ b2, float* __restrict__ imp) {
  int row = blockIdx.x, tid = threadIdx.x;
  __shared__ double red[256];
  double s = 0.0;
  const float* hr = h + (size_t)row * HID;
  for (int k = tid; k < HID; k += 256) s = fma((double)hr[k], (double)w2[k], s);
  red[tid] = s;
  __syncthreads();
  for (int off = 128; off > 0; off >>= 1) {
    if (tid < off) red[tid] += red[tid + off];
    __syncthreads();
  }
  if (tid == 0) {
    float logit = (float)(red[0] + (double)b2[0]);          // f32 store point
    double sg = 1.0 / (1.0 + exp(-(double)logit));
    imp[row] = (float)sg;                                   // f32 store point
  }
}

// ---------------------------------------------------------------------------
// per-batch min-max normalize in f32, then w = max(norm, 0.1f)
// ---------------------------------------------------------------------------
__global__ __launch_bounds__(512)
void cc_minmax(const float* __restrict__ imp, float* __restrict__ w) {
  int b = blockIdx.x, tid = threadIdx.x;
  __shared__ float mn[512], mx[512];
  float v = imp[b * SEQ + tid];
  mn[tid] = v; mx[tid] = v;
  __syncthreads();
  for (int off = 256; off > 0; off >>= 1) {
    if (tid < off) {
      mn[tid] = fminf(mn[tid], mn[tid + off]);
      mx[tid] = fmaxf(mx[tid], mx[tid + off]);
    }
    __syncthreads();
  }
  float lo = mn[0], hi = mx[0];
  float nv = (hi > lo) ? (v - lo) / (hi - lo) : v;
  w[b * SEQ + tid] = fmaxf(nv, 0.1f);
}

// ---------------------------------------------------------------------------
// row L2 norms of x: exact f64 sumsq, sqrt, rounded to f32, clamp 1e-12f
// ---------------------------------------------------------------------------
__global__ __launch_bounds__(256)
void cc_rownorm(const float* __restrict__ x, float* __restrict__ rn) {
  int row = blockIdx.x, tid = threadIdx.x;
  __shared__ double red[256];
  double s = 0.0;
  const float* xr = x + (size_t)row * DIM;
  for (int k = tid; k < DIM; k += 256) {
    double v = xr[k];
    s = fma(v, v, s);
  }
  red[tid] = s;
  __syncthreads();
  for (int off = 128; off > 0; off >>= 1) {
    if (tid < off) red[tid] += red[tid + off];
    __syncthreads();
  }
  if (tid == 0) rn[row] = fmaxf((float)sqrt(red[0]), 1e-12f);
}

// ---------------------------------------------------------------------------
// score[b,s,t]: xn = x/rn (f32 div at staging), f64-exact dot -> f32 sim,
// wprod f32 mul, score = sim/wprod f32 div; diag -1.0f.  BK=32, f64 LDS.
// ---------------------------------------------------------------------------
__global__ __launch_bounds__(256)
void cc_gemm_score(const float* __restrict__ X, const float* __restrict__ rn,
                   const float* __restrict__ w, float* __restrict__ score) {
  const int b = blockIdx.z;
  __shared__ double As[BK][66];
  __shared__ double Bs[BK][66];
  int tid = threadIdx.x;
  int tx = tid % 16, ty = tid / 16;
  int s0 = blockIdx.y * 64, t0 = blockIdx.x * 64;
  const float* Xb = X + (size_t)b * SEQ * DIM;
  const float* rnb = rn + b * SEQ;
  double acc[4][4] = {};
  for (int k0 = 0; k0 < DIM; k0 += BK) {
#pragma unroll
    for (int u = 0; u < 8; ++u) {
      int l = tid + u * 256;
      int r = l >> 5, k = l & 31;
      As[k][r] = (double)(Xb[(size_t)(s0 + r) * DIM + k0 + k] / rnb[s0 + r]);
      Bs[k][r] = (double)(Xb[(size_t)(t0 + r) * DIM + k0 + k] / rnb[t0 + r]);
    }
    __syncthreads();
#pragma unroll
    for (int k = 0; k < BK; ++k) {
      double a0 = As[k][ty * 4 + 0], a1 = As[k][ty * 4 + 1];
      double a2 = As[k][ty * 4 + 2], a3 = As[k][ty * 4 + 3];
      double b0 = Bs[k][tx * 4 + 0], b1 = Bs[k][tx * 4 + 1];
      double b2 = Bs[k][tx * 4 + 2], b3 = Bs[k][tx * 4 + 3];
      acc[0][0] = fma(a0, b0, acc[0][0]); acc[0][1] = fma(a0, b1, acc[0][1]);
      acc[0][2] = fma(a0, b2, acc[0][2]); acc[0][3] = fma(a0, b3, acc[0][3]);
      acc[1][0] = fma(a1, b0, acc[1][0]); acc[1][1] = fma(a1, b1, acc[1][1]);
      acc[1][2] = fma(a1, b2, acc[1][2]); acc[1][3] = fma(a1, b3, acc[1][3]);
      acc[2][0] = fma(a2, b0, acc[2][0]); acc[2][1] = fma(a2, b1, acc[2][1]);
      acc[2][2] = fma(a2, b2, acc[2][2]); acc[2][3] = fma(a2, b3, acc[2][3]);
      acc[3][0] = fma(a3, b0, acc[3][0]); acc[3][1] = fma(a3, b1, acc[3][1]);
      acc[3][2] = fma(a3, b2, acc[3][2]); acc[3][3] = fma(a3, b3, acc[3][3]);
    }
    __syncthreads();
  }
#pragma unroll
  for (int i = 0; i < 4; ++i)
#pragma unroll
    for (int j = 0; j < 4; ++j) {
      int s = s0 + ty * 4 + i, t = t0 + tx * 4 + j;
      float v;
      if (s == t) v = -1.0f;
      else {
        float sim = (float)acc[i][j];                       // f32 store point
        float wp = w[b * SEQ + s] * w[b * SEQ + t];         // f32 multiply
        v = sim / wp;                                       // f32 divide
      }
      score[((size_t)b * SEQ + s) * SEQ + t] = v;
    }
}

// ---------------------------------------------------------------------------
// Greedy pair selection: ONE WAVE per batch, wave-synchronous.
// Lane owns 8 rows (rmax/rarg in registers). Tie-breaks identical to round-4
// (flat argmax: smaller row, then smaller col).
// ---------------------------------------------------------------------------
__global__ __launch_bounds__(64)
void cc_greedy(const float* __restrict__ score, int* __restrict__ pi,
               int* __restrict__ pj, unsigned char* __restrict__ availg) {
  const int b = blockIdx.x;
  const float* S = score + (size_t)b * SEQ * SEQ;
  const int lane = threadIdx.x;
  __shared__ unsigned char avail[SEQ];
  __shared__ int spi[NPAIRS], spj[NPAIRS];
  float rmax8[8];
  int rarg8[8];
  unsigned am = 0xFFu;

  *(uint2*)&avail[lane * 8] = make_uint2(0x01010101u, 0x01010101u);
  __syncthreads();

  // initial cooperative row scans (row-major, cols ascending -> first-max)
  for (int r = 0; r < SEQ; ++r) {
    const float4* row4 = (const float4*)(S + (size_t)r * SEQ) + lane * 2;
    float4 v0 = row4[0], v1 = row4[1];
    float bv = v0.x; int bc = 0;
    if (v0.y > bv) { bv = v0.y; bc = 1; }
    if (v0.z > bv) { bv = v0.z; bc = 2; }
    if (v0.w > bv) { bv = v0.w; bc = 3; }
    if (v1.x > bv) { bv = v1.x; bc = 4; }
    if (v1.y > bv) { bv = v1.y; bc = 5; }
    if (v1.z > bv) { bv = v1.z; bc = 6; }
    if (v1.w > bv) { bv = v1.w; bc = 7; }
    bc += lane * 8;
#pragma unroll
    for (int off = 1; off < 64; off <<= 1) {
      float ov = __shfl_xor(bv, off, 64);
      int oc = __shfl_xor(bc, off, 64);
      if (ov > bv || (ov == bv && oc < bc)) { bv = ov; bc = oc; }
    }
    if ((r >> 3) == lane) {
#pragma unroll
      for (int q = 0; q < 8; ++q)
        if ((r & 7) == q) { rmax8[q] = bv; rarg8[q] = bc; }
    }
  }

  for (int t = 0; t < NPAIRS; ++t) {
    // best over my avail rows (rows ascending, strict > -> smaller row on tie)
    float bv = -INFINITY; int br = SEQ; int bc = 0;
#pragma unroll
    for (int q = 0; q < 8; ++q) {
      if (am & (1u << q)) {
        float v = rmax8[q];
        if (v > bv) { bv = v; br = lane * 8 + q; bc = rarg8[q]; }
      }
    }
#pragma unroll
    for (int off = 1; off < 64; off <<= 1) {
      float ov = __shfl_xor(bv, off, 64);
      int obr = __shfl_xor(br, off, 64);
      int obc = __shfl_xor(bc, off, 64);
      if (ov > bv || (ov == bv && obr < br)) { bv = ov; br = obr; bc = obc; }
    }
    const int i = br, j = bc;
    if (lane == 0) { spi[t] = i; spj[t] = j; avail[i] = 0; avail[j] = 0; }
    if ((i >> 3) == lane) am &= ~(1u << (i & 7));
    if ((j >> 3) == lane) am &= ~(1u << (j & 7));
    __syncthreads();
    // rescan rows whose cached argmax was invalidated
#pragma unroll
    for (int q = 0; q < 8; ++q) {
      bool need = ((am >> q) & 1u) && (rarg8[q] == i || rarg8[q] == j);
      unsigned long long mask = __ballot(need);
      while (mask) {
        int src = __ffsll((unsigned long long)mask) - 1;
        mask &= mask - 1;
        int r = src * 8 + q;
        const float4* row4 = (const float4*)(S + (size_t)r * SEQ) + lane * 2;
        float4 v0 = row4[0], v1 = row4[1];
        unsigned a0 = ((const unsigned*)avail)[lane * 2];
        unsigned a1 = ((const unsigned*)avail)[lane * 2 + 1];
        float nv = -INFINITY; int nc = 0;
        if ((a0 & 0x000000FFu) && v0.x > nv) { nv = v0.x; nc = 0; }
        if ((a0 & 0x0000FF00u) && v0.y > nv) { nv = v0.y; nc = 1; }
        if ((a0 & 0x00FF0000u) && v0.z > nv) { nv = v0.z; nc = 2; }
        if ((a0 & 0xFF000000u) && v0.w > nv) { nv = v0.w; nc = 3; }
        if ((a1 & 0x000000FFu) && v1.x > nv) { nv = v1.x; nc = 4; }
        if ((a1 & 0x0000FF00u) && v1.y > nv) { nv = v1.y; nc = 5; }
        if ((a1 & 0x00FF0000u) && v1.z > nv) { nv = v1.z; nc = 6; }
        if ((a1 & 0xFF000000u) && v1.w > nv) { nv = v1.w; nc = 7; }
        nc += lane * 8;
#pragma unroll
        for (int off = 1; off < 64; off <<= 1) {
          float ov = __shfl_xor(nv, off, 64);
          int oc = __shfl_xor(nc, off, 64);
          if (ov > nv || (ov == nv && oc < nc)) { nv = ov; nc = oc; }
        }
        if (lane == src) { rmax8[q] = nv; rarg8[q] = nc; }
      }
    }
    __syncthreads();
  }

  for (int t2 = lane; t2 < NPAIRS; t2 += 64) {
    pi[b * NPAIRS + t2] = spi[t2];
    pj[b * NPAIRS + t2] = spj[t2];
  }
#pragma unroll
  for (int q = 0; q < 8; ++q)
    availg[b * SEQ + lane * 8 + q] = avail[lane * 8 + q];
}

// ---------------------------------------------------------------------------
// unmerged index list via prefix sum (ascending order)
// ---------------------------------------------------------------------------
__global__ __launch_bounds__(512)
void cc_unmerged(const unsigned char* __restrict__ availg, int* __restrict__ un) {
  int b = blockIdx.x, tid = threadIdx.x;
  __shared__ int ps[SEQ];
  int flag = availg[b * SEQ + tid];
  ps[tid] = flag;
  __syncthreads();
  for (int off = 1; off < SEQ; off <<= 1) {
    int v = (tid >= off) ? ps[tid - off] : 0;
    __syncthreads();
    ps[tid] += v;
    __syncthreads();
  }
  int pos = ps[tid] - flag;
  if (flag && pos < NUN) un[b * NUN + pos] = tid;
}

// ---------------------------------------------------------------------------
// copy unmerged tokens to out rows [128, 384)
// ---------------------------------------------------------------------------
__global__ __launch_bounds__(256)
void cc_unmerged_copy(const float* __restrict__ x, const int* __restrict__ un,
                      float* __restrict__ out) {
  int idx = blockIdx.x;
  int b = idx / NUN, u_ = idx % NUN;
  int s = un[idx];
  const float4* src = (const float4*)(x + ((size_t)b * SEQ + s) * DIM);
  float4* dst = (float4*)(out + ((size_t)b * TLEN + NPAIRS + u_) * DIM);
  for (int u = threadIdx.x; u < DIM / 4; u += 256) dst[u] = src[u];
}

// ---------------------------------------------------------------------------
// m1 = gelu(pair @ mrg_w1 + b1); pair gathered from x via pi/pj on the fly.
// 128x128 tile, 8x8 per thread, f32. Single launch (M=2048, K=4096).
// ---------------------------------------------------------------------------
__global__ __launch_bounds__(256)
void cc_gemm_m1f(const float* __restrict__ x, const int* __restrict__ pi,
                 const int* __restrict__ pj, const float* __restrict__ B,
                 const float* __restrict__ bias, float* __restrict__ C) {
  const int N = DIM, K = 2 * DIM;
  __shared__ float As[16][132];
  __shared__ float Bs[16][132];
  int tid = threadIdx.x;
  int tx = tid % 16, ty = tid / 16;
  int m0 = blockIdx.y * 128, n0 = blockIdx.x * 128;
  float acc[8][8] = {};
  for (int k0 = 0; k0 < K; k0 += 16) {
    const int* tokArr = (k0 < DIM) ? pi : pj;
    const int kc0 = (k0 < DIM) ? k0 : k0 - DIM;
#pragma unroll
    for (int u = 0; u < 8; ++u) {
      int l = tid + u * 256;
      int r = l >> 4, k = l & 15;
      int mg = m0 + r;
      int bb = mg >> 7;
      int tok = tokArr[mg];
      As[k][r] = x[((size_t)bb * SEQ + tok) * DIM + kc0 + k];
      int kb = l >> 7, n = l & 127;
      Bs[kb][n] = B[(size_t)(k0 + kb) * N + n0 + n];
    }
    __syncthreads();
#pragma unroll
    for (int k = 0; k < 16; ++k) {
      float a[8], bb_[8];
      *(float4*)&a[0] = *(const float4*)&As[k][ty * 8];
      *(float4*)&a[4] = *(const float4*)&As[k][ty * 8 + 4];
      *(float4*)&bb_[0] = *(const float4*)&Bs[k][tx * 8];
      *(float4*)&bb_[4] = *(const float4*)&Bs[k][tx * 8 + 4];
#pragma unroll
      for (int i = 0; i < 8; ++i)
#pragma unroll
        for (int j = 0; j < 8; ++j)
          acc[i][j] = fmaf(a[i], bb_[j], acc[i][j]);
    }
    __syncthreads();
  }
#pragma unroll
  for (int i = 0; i < 8; ++i)
#pragma unroll
    for (int j = 0; j < 8; ++j) {
      int m = m0 + ty * 8 + i, n = n0 + tx * 8 + j;
      float v = acc[i][j] + bias[n];
      float g = 0.5f * v * (1.0f + erff(v * 0.70710678f));
      C[(size_t)m * N + n] = g;
    }
}

// ---------------------------------------------------------------------------
// merged = m1 @ mrg_w2 + b2, scattered into out rows [0,128). 128x128 tile.
// ---------------------------------------------------------------------------
__global__ __launch_bounds__(256)
void cc_gemm_m2c(const float* __restrict__ A, const float* __restrict__ B,
                 const float* __restrict__ bias, float* __restrict__ out) {
  const int N = DIM, K = DIM;
  __shared__ float As[16][132];
  __shared__ float Bs[16][132];
  int tid = threadIdx.x;
  int tx = tid % 16, ty = tid / 16;
  int m0 = blockIdx.y * 128, n0 = blockIdx.x * 128;
  float acc[8][8] = {};
  for (int k0 = 0; k0 < K; k0 += 16) {
#pragma unroll
    for (int u = 0; u < 8; ++u) {
      int l = tid + u * 256;
      int r = l >> 4, k = l & 15;
      As[k][r] = A[(size_t)(m0 + r) * K + k0 + k];
      int kb = l >> 7, n = l & 127;
      Bs[kb][n] = B[(size_t)(k0 + kb) * N + n0 + n];
    }
    __syncthreads();
#pragma unroll
    for (int k = 0; k < 16; ++k) {
      float a[8], bb_[8];
      *(float4*)&a[0] = *(const float4*)&As[k][ty * 8];
      *(float4*)&a[4] = *(const float4*)&As[k][ty * 8 + 4];
      *(float4*)&bb_[0] = *(const float4*)&Bs[k][tx * 8];
      *(float4*)&bb_[4] = *(const float4*)&Bs[k][tx * 8 + 4];
#pragma unroll
      for (int i = 0; i < 8; ++i)
#pragma unroll
        for (int j = 0; j < 8; ++j)
          acc[i][j] = fmaf(a[i], bb_[j], acc[i][j]);
    }
    __syncthreads();
  }
#pragma unroll
  for (int i = 0; i < 8; ++i)
#pragma unroll
    for (int j = 0; j < 8; ++j) {
      int m = m0 + ty * 8 + i, n = n0 + tx * 8 + j;
      int bb = m >> 7, p = m & 127;
      float v = acc[i][j] + bias[n];
      out[((size_t)bb * TLEN + p) * N + n] = v;
    }
}

extern "C" void kernel_launch(void* const* d_in, const int* in_sizes, int n_in,
                              void* d_out, int out_size, void* d_ws, size_t ws_size,
                              hipStream_t stream) {
  const float* x      = (const float*)d_in[0];
  const float* imp_w1 = (const float*)d_in[1];
  const float* imp_b1 = (const float*)d_in[2];
  const float* imp_w2 = (const float*)d_in[3];
  const float* imp_b2 = (const float*)d_in[4];
  const float* mrg_w1 = (const float*)d_in[5];
  const float* mrg_b1 = (const float*)d_in[6];
  const float* mrg_w2 = (const float*)d_in[7];
  const float* mrg_b2 = (const float*)d_in[8];
  float* out = (float*)d_out;

  // score (16 MB f32) lives in d_out — fully consumed before output writes.
  float* score = (float*)d_out;

  // workspace (~48.2 MB; rounds 2==3 bit-identical results imply ws >= 64 MB)
  char* ws = (char*)d_ws;
  float* hbuf  = (float*)ws;                               // 32 MB
  float* m1buf = (float*)(ws + ((size_t)32 << 20));        // 16 MB
  char* sm = ws + ((size_t)48 << 20);
  float* imp = (float*)sm;              sm += (size_t)BATCH * SEQ * 4;
  float* wv  = (float*)sm;              sm += (size_t)BATCH * SEQ * 4;
  float* rn  = (float*)sm;              sm += (size_t)BATCH * SEQ * 4;
  int* pi    = (int*)sm;                sm += (size_t)BATCH * NPAIRS * 4;
  int* pj    = (int*)sm;                sm += (size_t)BATCH * NPAIRS * 4;
  unsigned char* avail = (unsigned char*)sm; sm += (size_t)BATCH * SEQ;
  int* un    = (int*)sm;                sm += (size_t)BATCH * NUN * 4;

  cc_rownorm<<<BATCH * SEQ, 256, 0, stream>>>(x, rn);
  cc_gemm_h<<<dim3(HID / 64, BATCH * SEQ / 64), 256, 0, stream>>>(x, imp_w1, imp_b1, hbuf);
  cc_imp2<<<BATCH * SEQ, 256, 0, stream>>>(hbuf, imp_w2, imp_b2, imp);
  cc_minmax<<<BATCH, 512, 0, stream>>>(imp, wv);
  cc_gemm_score<<<dim3(SEQ / 64, SEQ / 64, BATCH), 256, 0, stream>>>(x, rn, wv, score);
  cc_greedy<<<BATCH, 64, 0, stream>>>(score, pi, pj, avail);
  cc_unmerged<<<BATCH, SEQ, 0, stream>>>(avail, un);
  // score (in d_out) dead from here; start writing outputs.
  cc_unmerged_copy<<<BATCH * NUN, 256, 0, stream>>>(x, un, out);
  cc_gemm_m1f<<<dim3(DIM / 128, BATCH * NPAIRS / 128), 256, 0, stream>>>(
      x, pi, pj, mrg_w1, mrg_b1, m1buf);
  cc_gemm_m2c<<<dim3(DIM / 128, BATCH * NPAIRS / 128), 256, 0, stream>>>(
      m1buf, mrg_w2, mrg_b2, out);
}